// Round 4
// baseline (203.794 us; speedup 1.0000x reference)
//
#include <hip/hip_runtime.h>
#include <math.h>

// AdaptiveTripletMarginLoss: B=65536 rows, D=256 fp32.
// R3 = R2 with the nontemporal-load type fixed: __builtin_nontemporal_load
// requires a Clang native vector, not HIP's float4 class -> ext_vector_type.
//  - 16 lanes/row, 4 rows/wave, shared butterfly
//  - NON-TEMPORAL loads: zero-reuse stream, don't allocate in caches
//  - fused finish: per-block atomicAdd to d_out; memset node zeroes d_out

#define D 256
#define TPB 256
#define ROWS_PER_BLOCK 16   // 4 waves * 4 rows/wave

typedef float nt_float4 __attribute__((ext_vector_type(4)));

__global__ __launch_bounds__(TPB, 8) void triplet_fused(
    const nt_float4* __restrict__ a4, const nt_float4* __restrict__ p4,
    const nt_float4* __restrict__ n4, float* __restrict__ out,
    int B, float invB)
{
    const int lane = threadIdx.x & 63;
    const int waveInBlock = threadIdx.x >> 6;
    const int sub = lane >> 4;          // which of the wave's 4 rows
    const int sl  = lane & 15;          // lane within the 16-lane row group
    const int row = (blockIdx.x * 4 + waveInBlock) * 4 + sub;

    float sap = 0.0f, san = 0.0f, spn = 0.0f;

    if (row < B) {
        // row = 256 floats = 64 float4; 16 lanes * 4 chunks of float4
        const size_t b = (size_t)row * 64 + sl;
        const nt_float4 av0 = __builtin_nontemporal_load(a4 + b);
        const nt_float4 av1 = __builtin_nontemporal_load(a4 + b + 16);
        const nt_float4 av2 = __builtin_nontemporal_load(a4 + b + 32);
        const nt_float4 av3 = __builtin_nontemporal_load(a4 + b + 48);
        const nt_float4 pv0 = __builtin_nontemporal_load(p4 + b);
        const nt_float4 pv1 = __builtin_nontemporal_load(p4 + b + 16);
        const nt_float4 pv2 = __builtin_nontemporal_load(p4 + b + 32);
        const nt_float4 pv3 = __builtin_nontemporal_load(p4 + b + 48);
        const nt_float4 nv0 = __builtin_nontemporal_load(n4 + b);
        const nt_float4 nv1 = __builtin_nontemporal_load(n4 + b + 16);
        const nt_float4 nv2 = __builtin_nontemporal_load(n4 + b + 32);
        const nt_float4 nv3 = __builtin_nontemporal_load(n4 + b + 48);

        float d;
#define ACC3(AV, PV, NV)                                                   \
        d = AV.x - PV.x; sap = fmaf(d, d, sap);                            \
        d = AV.y - PV.y; sap = fmaf(d, d, sap);                            \
        d = AV.z - PV.z; sap = fmaf(d, d, sap);                            \
        d = AV.w - PV.w; sap = fmaf(d, d, sap);                            \
        d = AV.x - NV.x; san = fmaf(d, d, san);                            \
        d = AV.y - NV.y; san = fmaf(d, d, san);                            \
        d = AV.z - NV.z; san = fmaf(d, d, san);                            \
        d = AV.w - NV.w; san = fmaf(d, d, san);                            \
        d = PV.x - NV.x; spn = fmaf(d, d, spn);                            \
        d = PV.y - NV.y; spn = fmaf(d, d, spn);                            \
        d = PV.z - NV.z; spn = fmaf(d, d, spn);                            \
        d = PV.w - NV.w; spn = fmaf(d, d, spn);

        ACC3(av0, pv0, nv0)
        ACC3(av1, pv1, nv1)
        ACC3(av2, pv2, nv2)
        ACC3(av3, pv3, nv3)
#undef ACC3
    }

    // butterfly over the 16-lane group (xor 8,4,2,1 stay in-group);
    // one pass reduces all 4 rows of the wave simultaneously.
    #pragma unroll
    for (int off = 8; off >= 1; off >>= 1) {
        sap += __shfl_xor(sap, off, 64);
        san += __shfl_xor(san, off, 64);
        spn += __shfl_xor(spn, off, 64);
    }

    __shared__ float sm[ROWS_PER_BLOCK];
    if (sl == 0) {
        float v = 0.0f;
        if (row < B) {
            const float dap = sqrtf(sap);
            const float dan = sqrtf(san);
            const float dpn = sqrtf(spn);
            // exp(4*dap) ~ exp(90) -> inf -> term 0 (matches ref fp32)
            const float msim = 1.0f + 2.0f / (__expf(4.0f * dap) + 1e-6f);
            // exp(-4*dan+4) underflows vs 1e-6 -> term ~2e6 (dominates loss)
            const float mdis = 1.0f + 2.0f / (__expf(-4.0f * dan + 4.0f) + 1e-6f);
            v = dap - 0.5f * (dan + dpn) + msim + mdis;
        }
        sm[waveInBlock * 4 + sub] = v;
    }
    __syncthreads();
    if (threadIdx.x == 0) {
        float s = 0.0f;
        #pragma unroll
        for (int i = 0; i < ROWS_PER_BLOCK; ++i) s += sm[i];
        // pre-scaled: contributions ~500 each, total ~2e6; fp32 ordering
        // noise << 4e4 absmax threshold
        atomicAdd(out, s * invB);
    }
}

extern "C" void kernel_launch(void* const* d_in, const int* in_sizes, int n_in,
                              void* d_out, int out_size, void* d_ws, size_t ws_size,
                              hipStream_t stream) {
    const nt_float4* a = (const nt_float4*)d_in[0];
    const nt_float4* p = (const nt_float4*)d_in[1];
    const nt_float4* n = (const nt_float4*)d_in[2];
    float* out = (float*)d_out;

    const int B = in_sizes[0] / D;    // 65536
    const int nBlocks = (B + ROWS_PER_BLOCK - 1) / ROWS_PER_BLOCK;  // 4096

    (void)hipMemsetAsync(d_out, 0, sizeof(float), stream);  // d_out poisoned 0xAA
    triplet_fused<<<nBlocks, TPB, 0, stream>>>(a, p, n, out, B, 1.0f / (float)B);
}

// Round 5
// 179.432 us; speedup vs baseline: 1.1358x; 1.1358x over previous
//
#include <hip/hip_runtime.h>
#include <math.h>

// AdaptiveTripletMarginLoss: B=65536 rows, D=256 fp32.
// R4: one-generation launch, deep per-wave bursts.
//  - 8 rows/wave; each load instr = one full row (64 lanes x float4 = 1 KiB)
//  - 24 nontemporal 1-KiB loads issued up front per wave (8 KB/stream burst)
//  - full 64-lane butterfly all-reduces all 24 row-sums at once
//  - two-kernel finish (d_ws partials + final_reduce), no memset/atomics

#define D 256
#define TPB 256
#define ROWS_PER_WAVE 8
#define WAVES_PER_BLOCK 4
#define ROWS_PER_BLOCK 32   // 2048 blocks for B=65536

typedef float nt_float4 __attribute__((ext_vector_type(4)));

__global__ __launch_bounds__(TPB, 3) void triplet_partial(
    const nt_float4* __restrict__ a4, const nt_float4* __restrict__ p4,
    const nt_float4* __restrict__ n4, float* __restrict__ partial, int B)
{
    const int lane = threadIdx.x & 63;
    const int wib  = threadIdx.x >> 6;
    const int row0 = (blockIdx.x * WAVES_PER_BLOCK + wib) * ROWS_PER_WAVE;

    float sap[ROWS_PER_WAVE], san[ROWS_PER_WAVE], spn[ROWS_PER_WAVE];

    if (row0 + ROWS_PER_WAVE <= B) {
        // row r = 64 float4; load j covers row (row0+j) across the 64 lanes
        const size_t base = (size_t)row0 * 64 + lane;

        nt_float4 av[ROWS_PER_WAVE], pv[ROWS_PER_WAVE], nv[ROWS_PER_WAVE];
        #pragma unroll
        for (int j = 0; j < ROWS_PER_WAVE; ++j)
            av[j] = __builtin_nontemporal_load(a4 + base + (size_t)j * 64);
        #pragma unroll
        for (int j = 0; j < ROWS_PER_WAVE; ++j)
            pv[j] = __builtin_nontemporal_load(p4 + base + (size_t)j * 64);
        #pragma unroll
        for (int j = 0; j < ROWS_PER_WAVE; ++j)
            nv[j] = __builtin_nontemporal_load(n4 + base + (size_t)j * 64);

        #pragma unroll
        for (int j = 0; j < ROWS_PER_WAVE; ++j) {
            float d, s0, s1, s2;
            d = av[j].x - pv[j].x; s0 = d * d;
            d = av[j].y - pv[j].y; s0 = fmaf(d, d, s0);
            d = av[j].z - pv[j].z; s0 = fmaf(d, d, s0);
            d = av[j].w - pv[j].w; s0 = fmaf(d, d, s0);
            d = av[j].x - nv[j].x; s1 = d * d;
            d = av[j].y - nv[j].y; s1 = fmaf(d, d, s1);
            d = av[j].z - nv[j].z; s1 = fmaf(d, d, s1);
            d = av[j].w - nv[j].w; s1 = fmaf(d, d, s1);
            d = pv[j].x - nv[j].x; s2 = d * d;
            d = pv[j].y - nv[j].y; s2 = fmaf(d, d, s2);
            d = pv[j].z - nv[j].z; s2 = fmaf(d, d, s2);
            d = pv[j].w - nv[j].w; s2 = fmaf(d, d, s2);
            sap[j] = s0; san[j] = s1; spn[j] = s2;
        }
    } else {
        #pragma unroll
        for (int j = 0; j < ROWS_PER_WAVE; ++j) {
            sap[j] = 0.0f; san[j] = 0.0f; spn[j] = 0.0f;
        }
    }

    // full 64-lane butterfly all-reduce of all 24 accumulators
    #pragma unroll
    for (int off = 32; off >= 1; off >>= 1) {
        #pragma unroll
        for (int j = 0; j < ROWS_PER_WAVE; ++j) {
            sap[j] += __shfl_xor(sap[j], off, 64);
            san[j] += __shfl_xor(san[j], off, 64);
            spn[j] += __shfl_xor(spn[j], off, 64);
        }
    }

    __shared__ float sm[WAVES_PER_BLOCK];
    if (lane == 0) {
        float local = 0.0f;
        if (row0 + ROWS_PER_WAVE <= B) {
            #pragma unroll
            for (int j = 0; j < ROWS_PER_WAVE; ++j) {
                const float dap = sqrtf(sap[j]);
                const float dan = sqrtf(san[j]);
                const float dpn = sqrtf(spn[j]);
                // exp(4*dap) ~ exp(90) -> inf -> term 0 (matches ref fp32)
                const float msim = 1.0f + 2.0f / (__expf(4.0f * dap) + 1e-6f);
                // exp(-4*dan+4) underflows vs 1e-6 -> term ~2e6 (dominates)
                const float mdis = 1.0f + 2.0f / (__expf(-4.0f * dan + 4.0f) + 1e-6f);
                local += dap - 0.5f * (dan + dpn) + msim + mdis;
            }
        }
        sm[wib] = local;
    }
    __syncthreads();
    if (threadIdx.x == 0) {
        float s = 0.0f;
        #pragma unroll
        for (int i = 0; i < WAVES_PER_BLOCK; ++i) s += sm[i];
        partial[blockIdx.x] = s;
    }
}

__global__ __launch_bounds__(256) void final_reduce(
    const float* __restrict__ partial, float* __restrict__ out,
    int nPartial, float invB)
{
    float s = 0.0f;
    for (int i = threadIdx.x; i < nPartial; i += blockDim.x) s += partial[i];
    #pragma unroll
    for (int off = 32; off > 0; off >>= 1) s += __shfl_xor(s, off, 64);

    __shared__ float sm[4];
    const int lane = threadIdx.x & 63;
    const int w = threadIdx.x >> 6;
    if (lane == 0) sm[w] = s;
    __syncthreads();
    if (threadIdx.x == 0) out[0] = (sm[0] + sm[1] + sm[2] + sm[3]) * invB;
}

extern "C" void kernel_launch(void* const* d_in, const int* in_sizes, int n_in,
                              void* d_out, int out_size, void* d_ws, size_t ws_size,
                              hipStream_t stream) {
    const nt_float4* a = (const nt_float4*)d_in[0];
    const nt_float4* p = (const nt_float4*)d_in[1];
    const nt_float4* n = (const nt_float4*)d_in[2];
    float* out = (float*)d_out;
    float* partial = (float*)d_ws;   // nBlocks floats (8 KiB) scratch

    const int B = in_sizes[0] / D;   // 65536
    const int nBlocks = (B + ROWS_PER_BLOCK - 1) / ROWS_PER_BLOCK;  // 2048

    triplet_partial<<<nBlocks, TPB, 0, stream>>>(a, p, n, partial, B);
    final_reduce<<<1, 256, 0, stream>>>(partial, out, nBlocks, 1.0f / (float)B);
}